// Round 17
// baseline (15353.880 us; speedup 1.0000x reference)
//
#include <hip/hip_runtime.h>
#include <hip/hip_bf16.h>

#define TSTEPS 512
#define NSTEPS 128          // steps per chunk (4 chunks)
#define BATCH  64
#define HDIM   1024
#define NROWS  (TSTEPS*BATCH)   // 32768

typedef __attribute__((ext_vector_type(8))) short bf16x8;
typedef __attribute__((ext_vector_type(4))) float f32x4;

__device__ __forceinline__ unsigned short f2bf(float f){
    unsigned u = __float_as_uint(f);
    u += 0x7fffu + ((u >> 16) & 1u);
    return (unsigned short)(u >> 16);
}
__device__ __forceinline__ float bf2f(unsigned short s){
    return __uint_as_float(((unsigned)s) << 16);
}

// ---------------------------------------------------------------------------
// Contention-free broadcast grid barrier, 256 blocks (r11/r14/r15-proven).
// Private 128B lines; arrival slots region[b*32], release region[8192+b*32].
// Works with 1024-thread blocks: only threads <256 of block 0 poll/release.
// ---------------------------------------------------------------------------
__device__ __forceinline__ void gridbar(unsigned int* region, unsigned int epoch){
    unsigned int* slots = region;
    unsigned int* rel   = region + 8192;
    __syncthreads();    // all waves' vmem (incl. h swaps) acked at L3
    if (blockIdx.x == 0){
        const int i = threadIdx.x;
        if (i > 0 && i < 256){
            while (__hip_atomic_load(&slots[i*32], __ATOMIC_RELAXED, __HIP_MEMORY_SCOPE_AGENT) < epoch)
                __builtin_amdgcn_s_sleep(2);
        }
        __syncthreads();
        if (i < 256){
            unsigned int old = __hip_atomic_exchange(&rel[i*32], epoch,
                                   __ATOMIC_RELAXED, __HIP_MEMORY_SCOPE_AGENT);
            asm volatile("" :: "v"(old));
        }
    } else {
        if (threadIdx.x == 0){
            unsigned int old = __hip_atomic_exchange(&slots[blockIdx.x*32], epoch,
                                   __ATOMIC_RELAXED, __HIP_MEMORY_SCOPE_AGENT);
            asm volatile("" :: "v"(old));
            while (__hip_atomic_load(&rel[blockIdx.x*32], __ATOMIC_RELAXED, __HIP_MEMORY_SCOPE_AGENT) < epoch)
                __builtin_amdgcn_s_sleep(2);
        }
        __syncthreads();
    }
    asm volatile("" ::: "memory");  // no hoisting ring loads above
}

// ---------------------------------------------------------------------------
// W [1024][4096] fp32 -> WThi/WTlo [4096][1024] bf16 (transpose + split)
// ---------------------------------------------------------------------------
__global__ __launch_bounds__(256)
void split_transpose_w(const float* __restrict__ W,
                       unsigned short* __restrict__ WThi,
                       unsigned short* __restrict__ WTlo)
{
    __shared__ float tile[32][33];
    const int c0 = blockIdx.x * 32;
    const int k0 = blockIdx.y * 32;
    const int tx = threadIdx.x & 31, ty = threadIdx.x >> 5;
    #pragma unroll
    for (int r=0;r<4;++r)
        tile[ty + r*8][tx] = W[(size_t)(k0 + ty + r*8)*4096 + c0 + tx];
    __syncthreads();
    #pragma unroll
    for (int r=0;r<4;++r){
        float v = tile[tx][ty + r*8];
        unsigned short hi = f2bf(v);
        unsigned short lo = f2bf(v - bf2f(hi));
        WThi[(size_t)(c0 + ty + r*8)*1024 + k0 + tx] = hi;
        WTlo[(size_t)(c0 + ty + r*8)*1024 + k0 + tx] = lo;
    }
}

// ---------------------------------------------------------------------------
// W [1024][4096] fp32 -> Whi/Wlo [256 bid][16 j][1024 k] bf16 split,
// j = g*4+hj <-> col = g*1024 + bid*4 + hj   (MFMA B-operand layout)
// ---------------------------------------------------------------------------
__global__ __launch_bounds__(256)
void reorder_whh_t(const float* __restrict__ W,
                   unsigned short* __restrict__ Whi,
                   unsigned short* __restrict__ Wlo)
{
    const int bid = blockIdx.x;
    const int j  = threadIdx.x & 15;
    const int k0 = threadIdx.x >> 4;
    const int col = (j>>2)*1024 + bid*4 + (j&3);
    for (int k = k0; k < 1024; k += 16){
        float v = W[(size_t)k*4096 + col];
        unsigned short hi = f2bf(v);
        unsigned short lo = f2bf(v - bf2f(hi));
        Whi[((size_t)bid*16 + j)*1024 + k] = hi;
        Wlo[((size_t)bid*16 + j)*1024 + k] = lo;
    }
}

// ---------------------------------------------------------------------------
// Split-bf16 MFMA GEMM over one 8192-row chunk (proven structure, bf16 out):
//   gp[t][bid256][b][16],  j = g*4 + hj,  col = g*1024 + bid*4 + hj
// ---------------------------------------------------------------------------
__global__ __launch_bounds__(256)
void gemm_xw_split(const float* __restrict__ A,
                   const unsigned short* __restrict__ BThi,
                   const unsigned short* __restrict__ BTlo,
                   const float* __restrict__ bias, unsigned short* __restrict__ gp)
{
    __shared__ __align__(16) unsigned short Ahi[128*32];
    __shared__ __align__(16) unsigned short Alo[128*32];
    __shared__ __align__(16) unsigned short Bhi[128*32];
    __shared__ __align__(16) unsigned short Blo[128*32];

    const int tid = threadIdx.x;
    const int w = tid >> 6, l = tid & 63;
    const int bx = blockIdx.x & 31, by = blockIdx.x >> 5;
    const int row0 = by*128, col0 = bx*128;
    const int wrow = (w>>1)*64, wcol = (w&1)*64;

    const int srow  = l >> 2;
    const int skoff = (l & 3) * 8;

    const int arow  = tid >> 1;
    const int akoff = (tid & 1) * 16;
    const float* aptr = A + (size_t)(row0 + arow)*1024 + akoff;

    f32x4 acc[4][4];
    #pragma unroll
    for (int m=0;m<4;++m)
        #pragma unroll
        for (int n=0;n<4;++n)
            acc[m][n] = (f32x4){0.f,0.f,0.f,0.f};

    for (int k0=0; k0<1024; k0+=32){
        #pragma unroll
        for (int c=0;c<2;++c){
            const int i = w*2 + c;
            const unsigned short* gh = BThi + (size_t)(col0 + i*16 + srow)*1024 + k0 + skoff;
            const unsigned short* gl = BTlo + (size_t)(col0 + i*16 + srow)*1024 + k0 + skoff;
            __builtin_amdgcn_global_load_lds((const __attribute__((address_space(1))) void*)gh,
                (__attribute__((address_space(3))) void*)(Bhi + i*512), 16, 0, 0);
            __builtin_amdgcn_global_load_lds((const __attribute__((address_space(1))) void*)gl,
                (__attribute__((address_space(3))) void*)(Blo + i*512), 16, 0, 0);
        }
        {
            float4 x0 = *reinterpret_cast<const float4*>(aptr + k0);
            float4 x1 = *reinterpret_cast<const float4*>(aptr + k0 + 4);
            float4 x2 = *reinterpret_cast<const float4*>(aptr + k0 + 8);
            float4 x3 = *reinterpret_cast<const float4*>(aptr + k0 + 12);
            float xs[16] = {x0.x,x0.y,x0.z,x0.w, x1.x,x1.y,x1.z,x1.w,
                            x2.x,x2.y,x2.z,x2.w, x3.x,x3.y,x3.z,x3.w};
            unsigned short hs[16], ls[16];
            #pragma unroll
            for (int e=0;e<16;++e){
                hs[e] = f2bf(xs[e]);
                ls[e] = f2bf(xs[e] - bf2f(hs[e]));
            }
            #pragma unroll
            for (int q=0;q<4;++q){
                ushort4 h4; h4.x=hs[q*4]; h4.y=hs[q*4+1]; h4.z=hs[q*4+2]; h4.w=hs[q*4+3];
                ushort4 l4; l4.x=ls[q*4]; l4.y=ls[q*4+1]; l4.z=ls[q*4+2]; l4.w=ls[q*4+3];
                *reinterpret_cast<ushort4*>(&Ahi[arow*32 + akoff + q*4]) = h4;
                *reinterpret_cast<ushort4*>(&Alo[arow*32 + akoff + q*4]) = l4;
            }
        }
        __syncthreads();
        bf16x8 afh[4], afl[4], bfh[4], bfl[4];
        #pragma unroll
        for (int m=0;m<4;++m){
            const int off = (wrow + m*16 + (l&15))*32 + (l>>4)*8;
            afh[m] = *reinterpret_cast<const bf16x8*>(&Ahi[off]);
            afl[m] = *reinterpret_cast<const bf16x8*>(&Alo[off]);
        }
        #pragma unroll
        for (int n=0;n<4;++n){
            const int off = (wcol + n*16 + (l&15))*32 + (l>>4)*8;
            bfh[n] = *reinterpret_cast<const bf16x8*>(&Bhi[off]);
            bfl[n] = *reinterpret_cast<const bf16x8*>(&Blo[off]);
        }
        #pragma unroll
        for (int m=0;m<4;++m)
            #pragma unroll
            for (int n=0;n<4;++n){
                acc[m][n] = __builtin_amdgcn_mfma_f32_16x16x32_bf16(afh[m], bfh[n], acc[m][n], 0,0,0);
                acc[m][n] = __builtin_amdgcn_mfma_f32_16x16x32_bf16(afl[m], bfh[n], acc[m][n], 0,0,0);
                acc[m][n] = __builtin_amdgcn_mfma_f32_16x16x32_bf16(afh[m], bfl[n], acc[m][n], 0,0,0);
            }
        __syncthreads();
    }

    #pragma unroll
    for (int n=0;n<4;++n){
        const int n_g = col0 + wcol + n*16 + (l&15);
        const float bv = bias[n_g];
        const int g = n_g >> 10, hcol = n_g & 1023;
        const int bid = hcol >> 2, hj = hcol & 3;
        #pragma unroll
        for (int m=0;m<4;++m){
            #pragma unroll
            for (int r=0;r<4;++r){
                const int m_g = row0 + wrow + m*16 + (l>>4)*4 + r;
                const int t = m_g >> 6, b = m_g & 63;
                gp[(((size_t)t*256 + bid)*64 + b)*16 + g*4 + hj] = f2bf(acc[m][n][r] + bv);
            }
        }
    }
}

// ---------------------------------------------------------------------------
// FUSED two-layer MFMA recurrence, one chunk (NSTEPS steps, NSTEPS+1 rounds).
// 256 real blocks x 1024 threads = 16 waves/CU; vb = tid>>9:
//   vb0: layer-0, cols [bid*4,bid*4+4): gates = gp0[r] + h0[r-1]*W_hh0
//   vb1: layer-1 (one round behind, s=r-1):
//        gates = h0[s]*W_ih1 + h1[s-1]*W_hh1 + b1;  writes out1[s] directly.
// W fragments in VGPRs. h exchanged as split-bf16 rings (129 slots; slot
// NSTEPS = h_{-1} init): write via returning 64-bit swaps (ack == at L3),
// read via plain fresh-address loads. One grid barrier per round.
// ---------------------------------------------------------------------------
__global__ __launch_bounds__(1024)
void lstm_fused(const unsigned short* __restrict__ gp,
                const unsigned short* __restrict__ Wh0h, const unsigned short* __restrict__ Wh0l,
                const unsigned short* __restrict__ Wi1h, const unsigned short* __restrict__ Wi1l,
                const unsigned short* __restrict__ Wh1h, const unsigned short* __restrict__ Wh1l,
                const float* __restrict__ bias1, float* __restrict__ out1,
                unsigned short* __restrict__ r0h, unsigned short* __restrict__ r0l,
                unsigned short* __restrict__ r1h, unsigned short* __restrict__ r1l,
                float* __restrict__ ctg, float* __restrict__ hn, float* __restrict__ cn,
                unsigned int* __restrict__ bar, int first, int last)
{
    __shared__ float pacc[2][8][64*17];   // 69.6 KB [vb][w][b][j+pad]
    __shared__ float xwlds[64*17];        //  4.3 KB (vb0 only)
    __shared__ float hout[2][256];        //  2 KB

    const int tid  = threadIdx.x;
    const int vb   = tid >> 9;
    const int vt   = tid & 511;
    const int bidx = blockIdx.x;
    const int w = vt >> 6, l = vt & 63;
    const int kbase = w << 7;            // wave K-range [kbase, kbase+128)
    const int foff = kbase + (l>>4)*8;   // fragment k-offset for this lane

    // W fragments, resident in VGPRs for the whole chunk.
    bf16x8 wah[4], wal[4], wbh[4], wbl[4];
    {
        const size_t wo = ((size_t)bidx*16 + (l&15))*1024 + foff;
        const unsigned short* pah = (vb==0 ? Wh0h : Wi1h) + wo;
        const unsigned short* pal = (vb==0 ? Wh0l : Wi1l) + wo;
        #pragma unroll
        for (int ks=0; ks<4; ++ks){
            wah[ks] = *reinterpret_cast<const bf16x8*>(pah + ks*32);
            wal[ks] = *reinterpret_cast<const bf16x8*>(pal + ks*32);
        }
        if (vb == 1){
            const unsigned short* pbh = Wh1h + wo;
            const unsigned short* pbl = Wh1l + wo;
            #pragma unroll
            for (int ks=0; ks<4; ++ks){
                wbh[ks] = *reinterpret_cast<const bf16x8*>(pbh + ks*32);
                wbl[ks] = *reinterpret_cast<const bf16x8*>(pbl + ks*32);
            }
        }
    }

    float b1r[4] = {0.f,0.f,0.f,0.f};
    if (vb == 1 && vt < 256){
        const int col = bidx*4 + (vt>>6);
        #pragma unroll
        for (int g=0; g<4; ++g) b1r[g] = bias1[g*1024 + col];
    }

    float creg = 0.f;
    if (!first && vt < 256) creg = ctg[vb*65536 + bidx*256 + vt];
    if (first && vt < 64){   // zero init slot NSTEPS of this layer's ring
        unsigned short* rh = (vb==0) ? r0h : r1h;
        unsigned short* rl = (vb==0) ? r0l : r1l;
        unsigned long long o1 = __hip_atomic_exchange(
            reinterpret_cast<unsigned long long*>(rh + (size_t)NSTEPS*65536 + vt*1024 + bidx*4),
            0ull, __ATOMIC_RELAXED, __HIP_MEMORY_SCOPE_AGENT);
        unsigned long long o2 = __hip_atomic_exchange(
            reinterpret_cast<unsigned long long*>(rl + (size_t)NSTEPS*65536 + vt*1024 + bidx*4),
            0ull, __ATOMIC_RELAXED, __HIP_MEMORY_SCOPE_AGENT);
        asm volatile("" :: "v"(o1), "v"(o2));
    }
    gridbar(bar, 1);

    const int bq = vt & 63;
    const int hc = vt >> 6;              // phase-C col (vt<256)

    for (int r=0; r<=NSTEPS; ++r){
        if (vb == 0 && r < NSTEPS){
            if (vt < 128){   // xW slice (bf16) -> xwlds padded
                bf16x8 v = *reinterpret_cast<const bf16x8*>(
                    gp + (size_t)r*262144 + (size_t)bidx*1024 + vt*8);
                const int b = vt >> 1, j0 = (vt & 1)*8;
                float* xp = &xwlds[b*17 + j0];
                #pragma unroll
                for (int e=0;e<8;++e) xp[e] = bf2f((unsigned short)v[e]);
            }
            const int rs0 = (r > 0) ? r-1 : (first ? NSTEPS : NSTEPS-1);
            const unsigned short* hbh = r0h + (size_t)rs0*65536 + foff;
            const unsigned short* hbl = r0l + (size_t)rs0*65536 + foff;
            f32x4 acc[4];
            #pragma unroll
            for (int mt=0; mt<4; ++mt) acc[mt] = (f32x4){0.f,0.f,0.f,0.f};
            #pragma unroll
            for (int mt=0; mt<4; ++mt){
                const size_t row = (size_t)(mt*16 + (l&15)) * 1024;
                #pragma unroll
                for (int ks=0; ks<4; ++ks){
                    bf16x8 ah = *reinterpret_cast<const bf16x8*>(hbh + row + ks*32);
                    bf16x8 al = *reinterpret_cast<const bf16x8*>(hbl + row + ks*32);
                    acc[mt] = __builtin_amdgcn_mfma_f32_16x16x32_bf16(ah, wah[ks], acc[mt], 0,0,0);
                    acc[mt] = __builtin_amdgcn_mfma_f32_16x16x32_bf16(al, wah[ks], acc[mt], 0,0,0);
                    acc[mt] = __builtin_amdgcn_mfma_f32_16x16x32_bf16(ah, wal[ks], acc[mt], 0,0,0);
                }
            }
            #pragma unroll
            for (int mt=0; mt<4; ++mt)
                #pragma unroll
                for (int q=0; q<4; ++q)
                    pacc[0][w][(mt*16 + (l>>4)*4 + q)*17 + (l&15)] = acc[mt][q];
        } else if (vb == 1 && r >= 1){
            const unsigned short* xbh = r0h + (size_t)(r-1)*65536 + foff;
            const unsigned short* xbl = r0l + (size_t)(r-1)*65536 + foff;
            const int rs1 = (r >= 2) ? r-2 : (first ? NSTEPS : NSTEPS-1);
            const unsigned short* hbh = r1h + (size_t)rs1*65536 + foff;
            const unsigned short* hbl = r1l + (size_t)rs1*65536 + foff;
            f32x4 acc[4];
            #pragma unroll
            for (int mt=0; mt<4; ++mt) acc[mt] = (f32x4){0.f,0.f,0.f,0.f};
            #pragma unroll
            for (int mt=0; mt<4; ++mt){
                const size_t row = (size_t)(mt*16 + (l&15)) * 1024;
                #pragma unroll
                for (int ks=0; ks<4; ++ks){
                    bf16x8 xh = *reinterpret_cast<const bf16x8*>(xbh + row + ks*32);
                    bf16x8 xl = *reinterpret_cast<const bf16x8*>(xbl + row + ks*32);
                    acc[mt] = __builtin_amdgcn_mfma_f32_16x16x32_bf16(xh, wah[ks], acc[mt], 0,0,0);
                    acc[mt] = __builtin_amdgcn_mfma_f32_16x16x32_bf16(xl, wah[ks], acc[mt], 0,0,0);
                    acc[mt] = __builtin_amdgcn_mfma_f32_16x16x32_bf16(xh, wal[ks], acc[mt], 0,0,0);
                    bf16x8 ah = *reinterpret_cast<const bf16x8*>(hbh + row + ks*32);
                    bf16x8 al = *reinterpret_cast<const bf16x8*>(hbl + row + ks*32);
                    acc[mt] = __builtin_amdgcn_mfma_f32_16x16x32_bf16(ah, wbh[ks], acc[mt], 0,0,0);
                    acc[mt] = __builtin_amdgcn_mfma_f32_16x16x32_bf16(al, wbh[ks], acc[mt], 0,0,0);
                    acc[mt] = __builtin_amdgcn_mfma_f32_16x16x32_bf16(ah, wbl[ks], acc[mt], 0,0,0);
                }
            }
            #pragma unroll
            for (int mt=0; mt<4; ++mt)
                #pragma unroll
                for (int q=0; q<4; ++q)
                    pacc[1][w][(mt*16 + (l>>4)*4 + q)*17 + (l&15)] = acc[mt][q];
        }
        __syncthreads();

        const bool act = (vb==0) ? (r < NSTEPS) : (r >= 1);
        if (vt < 256 && act){
            float gs[4];
            #pragma unroll
            for (int g=0; g<4; ++g){
                const int idx = bq*17 + g*4 + hc;
                float s = (vb==0) ? xwlds[idx] : b1r[g];
                #pragma unroll
                for (int pw=0; pw<8; ++pw) s += pacc[vb][pw][idx];
                gs[g] = s;
            }
            float ig = 1.f/(1.f + __expf(-gs[0]));
            float fg = 1.f/(1.f + __expf(-gs[1]));
            float gg = tanhf(gs[2]);
            float og = 1.f/(1.f + __expf(-gs[3]));
            float c_new = fg * creg + ig * gg;
            float h_new = og * tanhf(c_new);
            creg = c_new;
            hout[vb][bq*4 + hc] = h_new;
            const int hcolg = bidx*4 + hc;
            if (vb==0 && last && r == NSTEPS-1){
                hn[(size_t)bq*1024 + hcolg] = h_new;
                cn[(size_t)bq*1024 + hcolg] = c_new;
            }
            if (vb==1 && last && r == NSTEPS){
                hn[65536 + (size_t)bq*1024 + hcolg] = h_new;
                cn[65536 + (size_t)bq*1024 + hcolg] = c_new;
            }
        }
        __syncthreads();

        if (vt < 64 && act){
            const int b = vt;
            float h0v = hout[vb][b*4+0], h1v = hout[vb][b*4+1];
            float h2v = hout[vb][b*4+2], h3v = hout[vb][b*4+3];
            unsigned short p0 = f2bf(h0v), p1 = f2bf(h1v), p2 = f2bf(h2v), p3 = f2bf(h3v);
            unsigned short q0 = f2bf(h0v - bf2f(p0)), q1 = f2bf(h1v - bf2f(p1));
            unsigned short q2 = f2bf(h2v - bf2f(p2)), q3 = f2bf(h3v - bf2f(p3));
            unsigned long long phi = (unsigned long long)p0 | ((unsigned long long)p1<<16)
                                   | ((unsigned long long)p2<<32) | ((unsigned long long)p3<<48);
            unsigned long long plo = (unsigned long long)q0 | ((unsigned long long)q1<<16)
                                   | ((unsigned long long)q2<<32) | ((unsigned long long)q3<<48);
            const int slot = (vb==0) ? r : r-1;
            unsigned short* rh = (vb==0) ? r0h : r1h;
            unsigned short* rl = (vb==0) ? r0l : r1l;
            unsigned long long o1 = __hip_atomic_exchange(
                reinterpret_cast<unsigned long long*>(rh + (size_t)slot*65536 + b*1024 + bidx*4),
                phi, __ATOMIC_RELAXED, __HIP_MEMORY_SCOPE_AGENT);
            unsigned long long o2 = __hip_atomic_exchange(
                reinterpret_cast<unsigned long long*>(rl + (size_t)slot*65536 + b*1024 + bidx*4),
                plo, __ATOMIC_RELAXED, __HIP_MEMORY_SCOPE_AGENT);
            asm volatile("" :: "v"(o1), "v"(o2));
            if (vb == 1)
                *reinterpret_cast<float4*>(&out1[(size_t)(r-1)*65536 + (size_t)b*1024 + bidx*4]) =
                    make_float4(h0v, h1v, h2v, h3v);
        }
        gridbar(bar, r + 2);   // syncthreads inside drains the swaps first
    }
    if (vt < 256) ctg[vb*65536 + bidx*256 + vt] = creg;
}

// ---------------------------------------------------------------------------
extern "C" void kernel_launch(void* const* d_in, const int* in_sizes, int n_in,
                              void* d_out, int out_size, void* d_ws, size_t ws_size,
                              hipStream_t stream)
{
    const float* x    = (const float*)d_in[0];
    const float* Wih0 = (const float*)d_in[1];
    const float* Whh0 = (const float*)d_in[2];
    const float* b0   = (const float*)d_in[3];
    const float* Wih1 = (const float*)d_in[4];
    const float* Whh1 = (const float*)d_in[5];
    const float* b1   = (const float*)d_in[6];

    float* out1 = (float*)d_out;
    float* hn   = out1 + (size_t)NROWS*HDIM;      // [2][64][1024]
    float* cn   = hn + 2*BATCH*HDIM;

    char* wsb = (char*)d_ws;
    unsigned short* gp    = (unsigned short*)wsb;                      //  67,108,864
    unsigned short* WThi0 = (unsigned short*)(wsb +  67108864ull);     //   8,388,608
    unsigned short* WTlo0 = (unsigned short*)(wsb +  75497472ull);     //   8,388,608
    unsigned short* Wh0h  = (unsigned short*)(wsb +  83886080ull);     //   8,388,608
    unsigned short* Wh0l  = (unsigned short*)(wsb +  92274688ull);     //   8,388,608
    unsigned short* Wi1h  = (unsigned short*)(wsb + 100663296ull);     //   8,388,608
    unsigned short* Wi1l  = (unsigned short*)(wsb + 109051904ull);     //   8,388,608
    unsigned short* Wh1h  = (unsigned short*)(wsb + 117440512ull);     //   8,388,608
    unsigned short* Wh1l  = (unsigned short*)(wsb + 125829120ull);     //   8,388,608
    unsigned short* r0h   = (unsigned short*)(wsb + 134217728ull);     //  16,908,288 (129 slots)
    unsigned short* r0l   = (unsigned short*)(wsb + 151126016ull);     //  16,908,288
    unsigned short* r1h   = (unsigned short*)(wsb + 168034304ull);     //  16,908,288
    unsigned short* r1l   = (unsigned short*)(wsb + 184942592ull);     //  16,908,288
    float*          ctg   = (float*)(wsb + 201850880ull);              //     524,288
    unsigned int*   bar   = (unsigned int*)(wsb + 202375168ull);       //     262,144 (4 x 64KB)

    hipMemsetAsync(bar, 0, 262144, stream);
    split_transpose_w<<<dim3(128,32),256,0,stream>>>(Wih0, WThi0, WTlo0);
    reorder_whh_t<<<256,256,0,stream>>>(Whh0, Wh0h, Wh0l);
    reorder_whh_t<<<256,256,0,stream>>>(Wih1, Wi1h, Wi1l);
    reorder_whh_t<<<256,256,0,stream>>>(Whh1, Wh1h, Wh1l);

    for (int chunk=0; chunk<4; ++chunk){
        gemm_xw_split<<<2048,256,0,stream>>>(
            x + (size_t)chunk*NSTEPS*BATCH*HDIM, WThi0, WTlo0, b0, gp);

        const unsigned short* gpc = gp;
        const unsigned short* a0 = Wh0h; const unsigned short* a1 = Wh0l;
        const unsigned short* a2 = Wi1h; const unsigned short* a3 = Wi1l;
        const unsigned short* a4 = Wh1h; const unsigned short* a5 = Wh1l;
        const float* bb1 = b1;
        float* op = out1 + (size_t)chunk*NSTEPS*BATCH*HDIM;
        unsigned short* p0 = r0h; unsigned short* p1 = r0l;
        unsigned short* p2 = r1h; unsigned short* p3 = r1l;
        float* cg_ = ctg; float* h_ = hn; float* c_ = cn;
        unsigned int* br = bar + (size_t)chunk*16384;
        int first = (chunk == 0), last = (chunk == 3);
        void* args[19] = {(void*)&gpc, (void*)&a0, (void*)&a1, (void*)&a2, (void*)&a3,
                          (void*)&a4, (void*)&a5, (void*)&bb1, (void*)&op,
                          (void*)&p0, (void*)&p1, (void*)&p2, (void*)&p3,
                          (void*)&cg_, (void*)&h_, (void*)&c_,
                          (void*)&br, (void*)&first, (void*)&last};
        hipLaunchCooperativeKernel(reinterpret_cast<void*>(&lstm_fused),
                                   dim3(256), dim3(1024), args, 0, stream);
    }
}